// Round 1
// baseline (262.172 us; speedup 1.0000x reference)
//
#include <hip/hip_runtime.h>
#include <hip/hip_bf16.h>
#include <hip/hip_fp16.h>
#include <math.h>

// GCN link prediction. R12 = R11 structure (LDS-staged counting sort by dest
// col + CSR gather aggregation) with the gather kernels rebuilt around
// 2-lanes-per-node x uint4 (16B) message loads: one wave now retires 32 edges
// per gather instruction (was 8 edges x 4B half2). 4x fewer VMEM instrs, ~2x
// fewer VALU instrs per edge, identical fp32 accumulation order per channel.
//   deg[v] = incount(col==v)+1 ; dinv = rsqrt(deg)
//   ts[v]  = (h[v]@W)*dinv[v]          (fp16 gather tables, L2-resident)
//   h'[c]  = act(dinv[c]*(sum_{e:col=c} ts[row_e] + ts[c]) + b)
//   score  = sigmoid(dot(h2[row], h2[col]))

#define BSH 9
#define BSZ 512            // nodes per bucket -> NBUK = 196 (<= 256)
#define MAXCH 3200         // edges per chunk (multiple of 4)
#define MAXCHUNKS 1024

// ---- Phase A: per-(chunk,bucket) histogram -> M[b][NBUK] ----
__global__ __launch_bounds__(512) void pA(const int* __restrict__ col,
                                          int* __restrict__ M, int E, int CH, int NBUK) {
    __shared__ int hist[256];
    const int t = threadIdx.x, b = blockIdx.x;
    if (t < 256) hist[t] = 0;
    __syncthreads();
    const int s = b * CH, e = min(E, s + CH);
    const int n4 = (e - s) >> 2;                 // CH % 4 == 0 -> 16B-aligned
    const int4* c4 = (const int4*)(col + s);
    for (int i = t; i < n4; i += 512) {
        int4 c = c4[i];
        atomicAdd(&hist[c.x >> BSH], 1);
        atomicAdd(&hist[c.y >> BSH], 1);
        atomicAdd(&hist[c.z >> BSH], 1);
        atomicAdd(&hist[c.w >> BSH], 1);
    }
    for (int i = s + (n4 << 2) + t; i < e; i += 512) atomicAdd(&hist[col[i] >> BSH], 1);
    __syncthreads();
    for (int i = t; i < NBUK; i += 512) M[b * NBUK + i] = hist[i];
}

// ---- Phase B1: per-bucket exclusive scan over CN chunks (CN <= 1024) ----
__global__ __launch_bounds__(1024) void pB1(int* __restrict__ M, int* __restrict__ T,
                                            int NBUK, int CN) {
    __shared__ int s[1024];
    const int t = threadIdx.x, k = blockIdx.x;
    int own = (t < CN) ? M[t * NBUK + k] : 0;
    s[t] = own;
    __syncthreads();
    for (int d = 1; d < 1024; d <<= 1) {
        int add = (t >= d) ? s[t - d] : 0;
        __syncthreads();
        s[t] += add;
        __syncthreads();
    }
    if (t < CN) M[t * NBUK + k] = s[t] - own;
    if (t == 1023) T[k] = s[1023];
}

// ---- Phase B2: exclusive scan of bucket totals -> S[0..NBUK]; also start[N]=E ----
__global__ __launch_bounds__(512) void pB2(const int* __restrict__ T, int* __restrict__ S,
                                           int* __restrict__ start, int NBUK, int N, int E) {
    __shared__ int s[512];
    const int t = threadIdx.x;
    int own = (t < NBUK) ? T[t] : 0;
    s[t] = own;
    __syncthreads();
    for (int d = 1; d < 512; d <<= 1) {
        int add = (t >= d) ? s[t - d] : 0;
        __syncthreads();
        s[t] += add;
        __syncthreads();
    }
    if (t < NBUK) S[t] = s[t] - own;
    if (t == 511) S[NBUK] = s[511];
    if (t == 0) start[N] = E;
}

// ---- Phase C: LDS-staged bucket placement -> coalesced run writes ----
__global__ __launch_bounds__(512) void pC(const int* __restrict__ row, const int* __restrict__ col,
                                          const int* __restrict__ M, const int* __restrict__ S,
                                          unsigned int* __restrict__ ebuf, int E, int CH, int NBUK) {
    __shared__ unsigned int se[MAXCH];        // chunk edges, bucket-ordered
    __shared__ unsigned short pk[MAXCH];      // bucket id per LDS slot
    __shared__ int lhist[256], lbase[256], lcur[256], gbase[256];
    const int t = threadIdx.x, b = blockIdx.x;
    if (t < 256) lhist[t] = 0;
    __syncthreads();
    const int s = b * CH, e = min(E, s + CH);
    const int cnt = e - s;
    const int n4 = cnt >> 2;
    const int4* c4 = (const int4*)(col + s);
    const int4* r4 = (const int4*)(row + s);
    for (int i = t; i < n4; i += 512) {
        int4 c = c4[i];
        atomicAdd(&lhist[c.x >> BSH], 1);
        atomicAdd(&lhist[c.y >> BSH], 1);
        atomicAdd(&lhist[c.z >> BSH], 1);
        atomicAdd(&lhist[c.w >> BSH], 1);
    }
    for (int i = (n4 << 2) + t; i < cnt; i += 512) atomicAdd(&lhist[col[s + i] >> BSH], 1);
    __syncthreads();
    {   // 256-wide exclusive scan of lhist -> lbase (scratch in lcur); threads 0-255
        int own = (t < 256) ? lhist[t] : 0;
        if (t < 256) lcur[t] = own;
        __syncthreads();
        for (int d = 1; d < 256; d <<= 1) {
            int add = (t < 256 && t >= d) ? lcur[t - d] : 0;
            __syncthreads();
            if (t < 256) lcur[t] += add;
            __syncthreads();
        }
        if (t < 256) {
            lbase[t] = lcur[t] - own;
            lcur[t] = lcur[t] - own;
        }
        __syncthreads();
        if (t < NBUK) gbase[t] = S[t] + M[b * NBUK + t] - lbase[t];
    }
    __syncthreads();
    // placement into LDS (bucket-ordered)
    for (int i = t; i < n4; i += 512) {
        int4 c = c4[i];
        int4 r = r4[i];
        int k0 = c.x >> BSH, p0 = atomicAdd(&lcur[k0], 1);
        se[p0] = ((unsigned int)(c.x & (BSZ - 1)) << 17) | (unsigned int)r.x; pk[p0] = (unsigned short)k0;
        int k1 = c.y >> BSH, p1 = atomicAdd(&lcur[k1], 1);
        se[p1] = ((unsigned int)(c.y & (BSZ - 1)) << 17) | (unsigned int)r.y; pk[p1] = (unsigned short)k1;
        int k2 = c.z >> BSH, p2 = atomicAdd(&lcur[k2], 1);
        se[p2] = ((unsigned int)(c.z & (BSZ - 1)) << 17) | (unsigned int)r.z; pk[p2] = (unsigned short)k2;
        int k3 = c.w >> BSH, p3 = atomicAdd(&lcur[k3], 1);
        se[p3] = ((unsigned int)(c.w & (BSZ - 1)) << 17) | (unsigned int)r.w; pk[p3] = (unsigned short)k3;
    }
    for (int i = (n4 << 2) + t; i < cnt; i += 512) {
        int c = col[s + i], r = row[s + i];
        int k = c >> BSH, p = atomicAdd(&lcur[k], 1);
        se[p] = ((unsigned int)(c & (BSZ - 1)) << 17) | (unsigned int)r; pk[p] = (unsigned short)k;
    }
    __syncthreads();
    // coalesced write-out: consecutive LDS slots in a bucket -> consecutive global
    for (int i = t; i < cnt; i += 512) {
        int k = pk[i];
        ebuf[gbase[k] + i] = se[i];
    }
}

// ---- Phase C2: in-bucket counting sort by local col; emits dinv and CSR start ----
__global__ __launch_bounds__(1024) void pC2(const unsigned int* __restrict__ ebuf,
                                            const int* __restrict__ S,
                                            unsigned int* __restrict__ ebuf2,
                                            float* __restrict__ dinv,
                                            int* __restrict__ start, int N) {
    __shared__ int h[BSZ], sc[BSZ], cur[BSZ];
    const int t = threadIdx.x, k = blockIdx.x;
    if (t < BSZ) h[t] = 0;
    __syncthreads();
    const int s = S[k], e = S[k + 1];
    for (int i = s + t; i < e; i += 1024) atomicAdd(&h[ebuf[i] >> 17], 1);
    __syncthreads();
    if (t < BSZ) sc[t] = h[t];
    __syncthreads();
    for (int d = 1; d < BSZ; d <<= 1) {
        int add = (t < BSZ && t >= d) ? sc[t - d] : 0;
        __syncthreads();
        if (t < BSZ) sc[t] += add;
        __syncthreads();
    }
    if (t < BSZ) {
        cur[t] = sc[t] - h[t];             // exclusive scan
        const int v = (k << BSH) + t;
        if (v < N) {
            dinv[v] = rsqrtf((float)h[t] + 1.0f);
            start[v] = s + cur[t];
        }
    }
    __syncthreads();
    for (int i = s + t; i < e; i += 1024) {
        unsigned int w = ebuf[i];
        int p = atomicAdd(&cur[w >> 17], 1);
        ebuf2[s + p] = w;
    }
}

// ---- GEMM1: ts1h[v] = half((x[v] @ W1) * dinv[v]) ----
__global__ __launch_bounds__(256) void k_gemm1(
    const float* __restrict__ x, const float* __restrict__ W1,
    const float* __restrict__ dinv, __half* __restrict__ ts, int N) {
    __shared__ float wsT[16 * 132];
    const int tid = threadIdx.x;
    for (int idx = tid; idx < 2048; idx += 256) {
        int k = idx >> 4, c = idx & 15;
        wsT[c * 132 + k] = W1[idx];
    }
    __syncthreads();
    const int n = blockIdx.x * 256 + tid;
    if (n >= N) return;
    const float4* xr = (const float4*)(x + (size_t)n * 128);
    float acc[16];
    #pragma unroll
    for (int c = 0; c < 16; ++c) acc[c] = 0.f;
    #pragma unroll 4
    for (int k4 = 0; k4 < 32; ++k4) {
        float4 a = xr[k4];
        #pragma unroll
        for (int c = 0; c < 16; ++c) {
            const float4 w = *(const float4*)&wsT[c * 132 + k4 * 4];
            acc[c] = fmaf(a.x, w.x, fmaf(a.y, w.y, fmaf(a.z, w.z, fmaf(a.w, w.w, acc[c]))));
        }
    }
    float dv = dinv[n];
    union { __half h[16]; uint4 u[2]; } o;
    #pragma unroll
    for (int c = 0; c < 16; ++c) o.h[c] = __float2half(acc[c] * dv);
    uint4* dst = (uint4*)(ts + (size_t)n * 16);
    dst[0] = o.u[0]; dst[1] = o.u[1];
}

// Unpack-accumulate one uint4 (8 halves) into 8 fp32 channel accumulators.
#define ACC8(q) do {                                         \
    float2 f_;                                               \
    f_ = __half22float2(*(const __half2*)&(q).x); a0 += f_.x; a1 += f_.y; \
    f_ = __half22float2(*(const __half2*)&(q).y); a2 += f_.x; a3 += f_.y; \
    f_ = __half22float2(*(const __half2*)&(q).z); a4 += f_.x; a5 += f_.y; \
    f_ = __half22float2(*(const __half2*)&(q).w); a6 += f_.x; a7 += f_.y; \
} while (0)

// ---- Layer-1 aggregation: 2 lanes/node, 16B gather loads, 8-deep unroll,
//      fused bias/ReLU + 16x16 W2 via one xor-shuffle pair exchange ----
__global__ __launch_bounds__(256) void pGat1(
    const unsigned int* __restrict__ ebuf2, const int* __restrict__ start,
    const uint4* __restrict__ tsq, const float* __restrict__ dinv,
    const float* __restrict__ b1, const float* __restrict__ W2,
    uint4* __restrict__ ts2q, int N) {
    __shared__ float w2s[256];
    const int tid = threadIdx.x;
    w2s[tid] = W2[tid];
    __syncthreads();
    const int p = tid & 1;                 // half: channels 8p..8p+7
    const int v = blockIdx.x * 128 + (tid >> 1);
    if (v >= N) return;
    const int s = start[v], e = start[v + 1];
    float a0 = 0.f, a1 = 0.f, a2 = 0.f, a3 = 0.f, a4 = 0.f, a5 = 0.f, a6 = 0.f, a7 = 0.f;
    int i = s;
    for (; i + 8 <= e; i += 8) {
        uint4 q0 = tsq[((size_t)(ebuf2[i    ] & 0x1FFFF) << 1) + p];
        uint4 q1 = tsq[((size_t)(ebuf2[i + 1] & 0x1FFFF) << 1) + p];
        uint4 q2 = tsq[((size_t)(ebuf2[i + 2] & 0x1FFFF) << 1) + p];
        uint4 q3 = tsq[((size_t)(ebuf2[i + 3] & 0x1FFFF) << 1) + p];
        uint4 q4 = tsq[((size_t)(ebuf2[i + 4] & 0x1FFFF) << 1) + p];
        uint4 q5 = tsq[((size_t)(ebuf2[i + 5] & 0x1FFFF) << 1) + p];
        uint4 q6 = tsq[((size_t)(ebuf2[i + 6] & 0x1FFFF) << 1) + p];
        uint4 q7 = tsq[((size_t)(ebuf2[i + 7] & 0x1FFFF) << 1) + p];
        ACC8(q0); ACC8(q1); ACC8(q2); ACC8(q3);
        ACC8(q4); ACC8(q5); ACC8(q6); ACC8(q7);
    }
    for (; i + 4 <= e; i += 4) {
        uint4 q0 = tsq[((size_t)(ebuf2[i    ] & 0x1FFFF) << 1) + p];
        uint4 q1 = tsq[((size_t)(ebuf2[i + 1] & 0x1FFFF) << 1) + p];
        uint4 q2 = tsq[((size_t)(ebuf2[i + 2] & 0x1FFFF) << 1) + p];
        uint4 q3 = tsq[((size_t)(ebuf2[i + 3] & 0x1FFFF) << 1) + p];
        ACC8(q0); ACC8(q1); ACC8(q2); ACC8(q3);
    }
    for (; i < e; ++i) {
        uint4 q0 = tsq[((size_t)(ebuf2[i] & 0x1FFFF) << 1) + p];
        ACC8(q0);
    }
    // self-loop message
    {
        uint4 sq = tsq[((size_t)v << 1) + p];
        ACC8(sq);
    }
    const float dv = dinv[v];
    const float4 bA = ((const float4*)b1)[2 * p];
    const float4 bB = ((const float4*)b1)[2 * p + 1];
    float h[8];
    h[0] = fmaxf(fmaf(dv, a0, bA.x), 0.f);
    h[1] = fmaxf(fmaf(dv, a1, bA.y), 0.f);
    h[2] = fmaxf(fmaf(dv, a2, bA.z), 0.f);
    h[3] = fmaxf(fmaf(dv, a3, bA.w), 0.f);
    h[4] = fmaxf(fmaf(dv, a4, bB.x), 0.f);
    h[5] = fmaxf(fmaf(dv, a5, bB.y), 0.f);
    h[6] = fmaxf(fmaf(dv, a6, bB.z), 0.f);
    h[7] = fmaxf(fmaf(dv, a7, bB.w), 0.f);
    // h @ W2 : lane p holds input+output channels 8p..8p+7; partner's inputs via xor-shuffle
    const int my = p * 8, ot = (1 - p) * 8;
    float o[8];
    #pragma unroll
    for (int c = 0; c < 8; ++c) o[c] = 0.f;
    #pragma unroll
    for (int j = 0; j < 8; ++j) {
        float hm = h[j];
        float ho = __shfl_xor(h[j], 1);
        #pragma unroll
        for (int c = 0; c < 8; ++c) {
            o[c] = fmaf(hm, w2s[(my + j) * 16 + my + c],
                   fmaf(ho, w2s[(ot + j) * 16 + my + c], o[c]));
        }
    }
    union { __half hh[8]; uint4 u; } ov;
    #pragma unroll
    for (int c = 0; c < 8; ++c) ov.hh[c] = __float2half(dv * o[c]);
    ts2q[((size_t)v << 1) + p] = ov.u;
}

// ---- Layer-2 aggregation: 2 lanes/node, 16B gather loads + bias ----
__global__ __launch_bounds__(256) void pGat2(
    const unsigned int* __restrict__ ebuf2, const int* __restrict__ start,
    const uint4* __restrict__ tsq, const float* __restrict__ dinv,
    const float* __restrict__ b2, uint4* __restrict__ h2q, int N) {
    const int tid = threadIdx.x;
    const int p = tid & 1;
    const int v = blockIdx.x * 128 + (tid >> 1);
    if (v >= N) return;
    const int s = start[v], e = start[v + 1];
    float a0 = 0.f, a1 = 0.f, a2 = 0.f, a3 = 0.f, a4 = 0.f, a5 = 0.f, a6 = 0.f, a7 = 0.f;
    int i = s;
    for (; i + 8 <= e; i += 8) {
        uint4 q0 = tsq[((size_t)(ebuf2[i    ] & 0x1FFFF) << 1) + p];
        uint4 q1 = tsq[((size_t)(ebuf2[i + 1] & 0x1FFFF) << 1) + p];
        uint4 q2 = tsq[((size_t)(ebuf2[i + 2] & 0x1FFFF) << 1) + p];
        uint4 q3 = tsq[((size_t)(ebuf2[i + 3] & 0x1FFFF) << 1) + p];
        uint4 q4 = tsq[((size_t)(ebuf2[i + 4] & 0x1FFFF) << 1) + p];
        uint4 q5 = tsq[((size_t)(ebuf2[i + 5] & 0x1FFFF) << 1) + p];
        uint4 q6 = tsq[((size_t)(ebuf2[i + 6] & 0x1FFFF) << 1) + p];
        uint4 q7 = tsq[((size_t)(ebuf2[i + 7] & 0x1FFFF) << 1) + p];
        ACC8(q0); ACC8(q1); ACC8(q2); ACC8(q3);
        ACC8(q4); ACC8(q5); ACC8(q6); ACC8(q7);
    }
    for (; i + 4 <= e; i += 4) {
        uint4 q0 = tsq[((size_t)(ebuf2[i    ] & 0x1FFFF) << 1) + p];
        uint4 q1 = tsq[((size_t)(ebuf2[i + 1] & 0x1FFFF) << 1) + p];
        uint4 q2 = tsq[((size_t)(ebuf2[i + 2] & 0x1FFFF) << 1) + p];
        uint4 q3 = tsq[((size_t)(ebuf2[i + 3] & 0x1FFFF) << 1) + p];
        ACC8(q0); ACC8(q1); ACC8(q2); ACC8(q3);
    }
    for (; i < e; ++i) {
        uint4 q0 = tsq[((size_t)(ebuf2[i] & 0x1FFFF) << 1) + p];
        ACC8(q0);
    }
    {
        uint4 sq = tsq[((size_t)v << 1) + p];
        ACC8(sq);
    }
    const float dv = dinv[v];
    const float4 bA = ((const float4*)b2)[2 * p];
    const float4 bB = ((const float4*)b2)[2 * p + 1];
    union { __half hh[8]; uint4 u; } ov;
    ov.hh[0] = __float2half(fmaf(dv, a0, bA.x));
    ov.hh[1] = __float2half(fmaf(dv, a1, bA.y));
    ov.hh[2] = __float2half(fmaf(dv, a2, bA.z));
    ov.hh[3] = __float2half(fmaf(dv, a3, bA.w));
    ov.hh[4] = __float2half(fmaf(dv, a4, bB.x));
    ov.hh[5] = __float2half(fmaf(dv, a5, bB.y));
    ov.hh[6] = __float2half(fmaf(dv, a6, bB.z));
    ov.hh[7] = __float2half(fmaf(dv, a7, bB.w));
    h2q[((size_t)v << 1) + p] = ov.u;
}

// ---- Edge scores (R8/R10-proven: 1 edge/thread, no NT) ----
__global__ void k_score(const int* __restrict__ row, const int* __restrict__ col,
                        const __half* __restrict__ h2h, float* __restrict__ out, int E) {
    int e = blockIdx.x * 256 + threadIdx.x;
    if (e < E) {
        union { uint4 u[2]; __half2 h[8]; } a, b;
        const uint4* pa = (const uint4*)(h2h + (size_t)row[e] * 16);
        const uint4* pb = (const uint4*)(h2h + (size_t)col[e] * 16);
        a.u[0] = pa[0]; a.u[1] = pa[1];
        b.u[0] = pb[0]; b.u[1] = pb[1];
        float d = 0.f;
        #pragma unroll
        for (int i = 0; i < 8; ++i) {
            float2 fa = __half22float2(a.h[i]);
            float2 fb = __half22float2(b.h[i]);
            d = fmaf(fa.x, fb.x, fmaf(fa.y, fb.y, d));
        }
        out[e] = 1.0f / (1.0f + __expf(-d));
    }
}

// ---------------- Fallback (R2 atomic path) ----------------
__global__ void k_countf(const int* __restrict__ col, float* __restrict__ deg, int E) {
    int e = blockIdx.x * 256 + threadIdx.x;
    if (e < E) atomicAdd(&deg[col[e]], 1.0f);
}
__global__ void k_dinvf(float* __restrict__ dinv, int N) {
    int v = blockIdx.x * 256 + threadIdx.x;
    if (v < N) dinv[v] = rsqrtf(dinv[v] + 1.0f);
}
__global__ __launch_bounds__(256) void k_gemm1f(
    const float* __restrict__ x, const float* __restrict__ W1,
    const float* __restrict__ dinv, float* __restrict__ ts, int N) {
    __shared__ float wsT[16 * 132];
    const int tid = threadIdx.x;
    for (int idx = tid; idx < 2048; idx += 256) {
        int k = idx >> 4, c = idx & 15;
        wsT[c * 132 + k] = W1[idx];
    }
    __syncthreads();
    const int n = blockIdx.x * 256 + tid;
    if (n >= N) return;
    const float4* xr = (const float4*)(x + (size_t)n * 128);
    float acc[16];
    #pragma unroll
    for (int c = 0; c < 16; ++c) acc[c] = 0.f;
    for (int k4 = 0; k4 < 32; ++k4) {
        float4 a = xr[k4];
        #pragma unroll
        for (int c = 0; c < 16; ++c) {
            const float4 w = *(const float4*)&wsT[c * 132 + k4 * 4];
            acc[c] = fmaf(a.x, w.x, fmaf(a.y, w.y, fmaf(a.z, w.z, fmaf(a.w, w.w, acc[c]))));
        }
    }
    float dv = dinv[n];
    float4* o = (float4*)(ts + (size_t)n * 16);
    #pragma unroll
    for (int q = 0; q < 4; ++q)
        o[q] = make_float4(acc[4*q] * dv, acc[4*q+1] * dv, acc[4*q+2] * dv, acc[4*q+3] * dv);
}
__global__ void k_scatter(const int* __restrict__ row, const int* __restrict__ col,
                          const float* __restrict__ ts, float* __restrict__ acc, int E) {
    int g = blockIdx.x * 256 + threadIdx.x;
    int e = g >> 4, c = g & 15;
    if (e < E) atomicAdd(&acc[(size_t)col[e] * 16 + c], ts[(size_t)row[e] * 16 + c]);
}
__global__ void k_finalize(float* __restrict__ acc, const float* __restrict__ ts,
                           const float* __restrict__ dinv, const float* __restrict__ b,
                           int N, int relu) {
    int g = blockIdx.x * 256 + threadIdx.x;
    int v = g >> 4, c = g & 15;
    if (v < N) {
        float h = dinv[v] * (acc[g] + ts[g]) + b[c];
        if (relu) h = fmaxf(h, 0.f);
        acc[g] = h;
    }
}
__global__ __launch_bounds__(256) void k_gemm2f(
    const float* __restrict__ h1, const float* __restrict__ W2,
    const float* __restrict__ dinv, float* __restrict__ ts2, int N) {
    __shared__ float hs[16 * 17];
    __shared__ float ws2[256];
    const int tid = threadIdx.x;
    const int base = blockIdx.x * 16;
    if (tid < 64) ((float4*)ws2)[tid] = ((const float4*)W2)[tid];
    if (tid >= 64 && tid < 128) {
        int t2 = tid - 64;
        float4 v4 = ((const float4*)(h1 + (size_t)base * 16))[t2];
        float* d = &hs[(t2 >> 2) * 17 + (t2 & 3) * 4];
        d[0] = v4.x; d[1] = v4.y; d[2] = v4.z; d[3] = v4.w;
    }
    __syncthreads();
    const int r = tid >> 4, c = tid & 15;
    float a = 0.f;
    #pragma unroll
    for (int kk = 0; kk < 16; ++kk) a = fmaf(hs[r * 17 + kk], ws2[kk * 16 + c], a);
    ts2[(size_t)(base + r) * 16 + c] = a * dinv[base + r];
}
__global__ void k_scoref(const int* __restrict__ row, const int* __restrict__ col,
                         const float* __restrict__ h2, float* __restrict__ out, int E) {
    int e = blockIdx.x * 256 + threadIdx.x;
    if (e < E) {
        const float4* a = (const float4*)(h2 + (size_t)row[e] * 16);
        const float4* b = (const float4*)(h2 + (size_t)col[e] * 16);
        float d = 0.f;
        #pragma unroll
        for (int i = 0; i < 4; ++i) {
            float4 u = a[i], v = b[i];
            d += u.x * v.x + u.y * v.y + u.z * v.z + u.w * v.w;
        }
        out[e] = 1.0f / (1.0f + __expf(-d));
    }
}

extern "C" void kernel_launch(void* const* d_in, const int* in_sizes, int n_in,
                              void* d_out, int out_size, void* d_ws, size_t ws_size,
                              hipStream_t stream) {
    const float* x  = (const float*)d_in[0];
    const int*   ei = (const int*)d_in[1];
    const float* W1 = (const float*)d_in[2];
    const float* b1 = (const float*)d_in[3];
    const float* W2 = (const float*)d_in[4];
    const float* b2 = (const float*)d_in[5];

    const int N = in_sizes[0] / 128;   // 100000
    const int E = in_sizes[1] / 2;     // 3200000
    const int* row = ei;
    const int* col = ei + E;
    float* out = (float*)d_out;

    const int NBUK = (N + BSZ - 1) / BSZ;          // 196
    const int CN = (E + MAXCH - 1) / MAXCH;        // 1000 chunks
    const int CH = MAXCH;                          // 3200, multiple of 4

    char* ws = (char*)d_ws;
    size_t off = 0;
    auto alloc = [&](size_t bytes) { void* p = ws + off; off += (bytes + 255) & ~(size_t)255; return p; };
    float*  dinv  = (float*)alloc((size_t)N * 4);
    __half* ts1h  = (__half*)alloc((size_t)N * 32);    // also h2h after pGat1
    __half* ts2h  = (__half*)alloc((size_t)N * 32);
    int*    start = (int*)alloc((size_t)(N + 1) * 4);
    int*    M     = (int*)alloc((size_t)CN * NBUK * 4);
    int*    T     = (int*)alloc((size_t)NBUK * 4);
    int*    S     = (int*)alloc((size_t)(NBUK + 1) * 4);
    unsigned int* ebuf  = (unsigned int*)alloc((size_t)E * 4);
    unsigned int* ebuf2 = (unsigned int*)alloc((size_t)E * 4);
    const size_t need = off;    // ~34 MB at N=100k, E=3.2M

    if (N <= 131072 && NBUK <= 256 && CN <= MAXCHUNKS && ws_size >= need) {
        pA <<<CN, 512, 0, stream>>>(col, M, E, CH, NBUK);
        pB1<<<NBUK, 1024, 0, stream>>>(M, T, NBUK, CN);
        pB2<<<1, 512, 0, stream>>>(T, S, start, NBUK, N, E);
        pC <<<CN, 512, 0, stream>>>(row, col, M, S, ebuf, E, CH, NBUK);
        pC2<<<NBUK, 1024, 0, stream>>>(ebuf, S, ebuf2, dinv, start, N);
        k_gemm1<<<(N + 255) / 256, 256, 0, stream>>>(x, W1, dinv, ts1h, N);
        pGat1<<<(N + 127) / 128, 256, 0, stream>>>(ebuf2, start, (const uint4*)ts1h, dinv, b1, W2,
                                                   (uint4*)ts2h, N);
        __half* h2h = ts1h;   // ts1h dead after pGat1
        pGat2<<<(N + 127) / 128, 256, 0, stream>>>(ebuf2, start, (const uint4*)ts2h, dinv, b2,
                                                   (uint4*)h2h, N);
        k_score<<<(E + 255) / 256, 256, 0, stream>>>(row, col, h2h, out, E);
    } else {
        // R2 fallback, fp32 buffers carved independently
        float* dinvF = (float*)ws;
        float* ts1F  = (float*)(ws + (size_t)N * 4);
        float* ts2F  = (float*)(ws + (size_t)N * 4 + (size_t)N * 64);
        hipMemsetAsync(dinvF, 0, (size_t)N * 4, stream);
        hipMemsetAsync(ts2F, 0, (size_t)N * 64, stream);
        k_countf<<<(E + 255) / 256, 256, 0, stream>>>(col, dinvF, E);
        k_dinvf<<<(N + 255) / 256, 256, 0, stream>>>(dinvF, N);
        k_gemm1f<<<(N + 255) / 256, 256, 0, stream>>>(x, W1, dinvF, ts1F, N);
        k_scatter<<<(E * 16) / 256, 256, 0, stream>>>(row, col, ts1F, ts2F, E);
        k_finalize<<<(N * 16 + 255) / 256, 256, 0, stream>>>(ts2F, ts1F, dinvF, b1, N, 1);
        k_gemm2f<<<N / 16, 256, 0, stream>>>(ts2F, W2, dinvF, ts1F, N);
        hipMemsetAsync(ts2F, 0, (size_t)N * 64, stream);
        k_scatter<<<(E * 16) / 256, 256, 0, stream>>>(row, col, ts1F, ts2F, E);
        k_finalize<<<(N * 16 + 255) / 256, 256, 0, stream>>>(ts2F, ts1F, dinvF, b2, N, 0);
        k_scoref<<<(E + 255) / 256, 256, 0, stream>>>(row, col, ts2F, out, E);
    }
}